// Round 6
// baseline (386.295 us; speedup 1.0000x reference)
//
#include <hip/hip_runtime.h>
#include <stdint.h>

#define B_BATCH 64
#define L_SEQ 2048
#define E_DIM 1024
#define A_DIM 512

typedef __attribute__((ext_vector_type(4))) float f32x4;
typedef __attribute__((ext_vector_type(8))) short bf16x8;
typedef __attribute__((ext_vector_type(2))) unsigned int u32x2;
typedef __attribute__((ext_vector_type(4))) unsigned int u32x4;

__device__ __forceinline__ unsigned short f2bf(float f) {
  unsigned u = __float_as_uint(f);
  u = (u + 0x7fffu + ((u >> 16) & 1u)) >> 16;  // RNE
  return (unsigned short)u;
}

__device__ __forceinline__ u32x2 packbf(f32x4 v) {
  u32x2 r;
  r.x = (unsigned)f2bf(v.x) | ((unsigned)f2bf(v.y) << 16);
  r.y = (unsigned)f2bf(v.z) | ((unsigned)f2bf(v.w) << 16);
  return r;
}

// A-tile LDS image: 128 rows x 64 B (32 bf16). 16B slot s of row n at slot s ^ ((n>>1)&3).
// Slot g holds k {4g..4g+3, 16+4g..16+4g+3} (frag k-order, proven R1-R5). 4 buffers of 8 KB.
#define BUFB 8192
#define BCHUNK 32768  // ws_B bytes per K-step: 512 cols x 64 B frag-chunks

// ---------------- K0: We_w (fp32 [1024,512]) -> ws_B bf16 in GEMM B-frag order -------------
__global__ void prep_we_kernel(const float* __restrict__ We, char* __restrict__ wsB) {
  int t = blockIdx.x * 256 + threadIdx.x;  // 65536 threads = 1 16B chunk each
  int lane = t & 63;
  int colblk = (t >> 6) & 31;
  int step = t >> 11;  // 0..31
  int nl = lane & 15, g = lane >> 4;
  int col = colblk * 16 + nl;
  int k0 = step * 32 + 4 * g;
  unsigned q0 = (unsigned)f2bf(We[(size_t)(k0 + 0) * A_DIM + col]) |
                ((unsigned)f2bf(We[(size_t)(k0 + 1) * A_DIM + col]) << 16);
  unsigned q1 = (unsigned)f2bf(We[(size_t)(k0 + 2) * A_DIM + col]) |
                ((unsigned)f2bf(We[(size_t)(k0 + 3) * A_DIM + col]) << 16);
  unsigned q2 = (unsigned)f2bf(We[(size_t)(k0 + 16) * A_DIM + col]) |
                ((unsigned)f2bf(We[(size_t)(k0 + 17) * A_DIM + col]) << 16);
  unsigned q3 = (unsigned)f2bf(We[(size_t)(k0 + 18) * A_DIM + col]) |
                ((unsigned)f2bf(We[(size_t)(k0 + 19) * A_DIM + col]) << 16);
  u32x4 v; v.x = q0; v.y = q1; v.z = q2; v.w = q3;
  *(u32x4*)(wsB + (size_t)t * 16) = v;
}

// ---------------- K1: dcomb[b][a] = decoder_hidden[b]·Wd_w[:,a] + Wd_b[a] + We_b[a] --------
__global__ void dec_comb_kernel(const float* __restrict__ dh, const float* __restrict__ Wd,
                                const float* __restrict__ Wdb, const float* __restrict__ Web,
                                float* __restrict__ dcomb) {
  __shared__ float sh[1024];
  const int b = blockIdx.x, tid = threadIdx.x;
  for (int i = tid; i < 1024; i += 256) sh[i] = dh[b * 1024 + i];
  __syncthreads();
  const int a = blockIdx.y * 256 + tid;
  float acc = Wdb[a] + Web[a];
#pragma unroll 4
  for (int e = 0; e < 1024; ++e) acc += sh[e] * Wd[(size_t)e * A_DIM + a];
  dcomb[b * A_DIM + a] = acc;
}

// ---------------- K2: fused score GEMM -----------------------------------------------------
// block: 128 rows x 512 cols, 8 waves, wave = 128x64. BK=32, 32 K-steps, 1 block/CU.
// A: HBM fp32 -> reg (DEPTH 4) -> bf16 -> LDS (4-buffer, swizzled). B: L2 bf16 frags -> reg
// (depth 1, issued BEFORE A so the vmcnt prefix-drain keeps A(t+3),A(t+4) in flight: 32-48 KB
// of HBM MLP per CU). Steady-state: vmcnt(8); never vmcnt(0) until the tail.
__global__ __launch_bounds__(512, 2) void score_gemm_kernel(
    const float* __restrict__ enc, const char* __restrict__ wsB,
    const float* __restrict__ dcomb, const float* __restrict__ wf,
    float* __restrict__ scoreOut) {
  __shared__ __align__(16) char smem[4 * BUFB];
  __shared__ float s_score[128];

  const int tid = threadIdx.x;
  const int lane = tid & 63;
  const int w = tid >> 6;      // 0..7
  const int g = lane >> 4;
  const int nl = lane & 15;
  const int gs = g ^ ((nl >> 1) & 3);   // swizzled read slot

  const int row0 = (int)blockIdx.x * 128;
  const int bb = row0 >> 11;

  if (tid < 128) s_score[tid] = 0.0f;

  const float* encA = enc + (size_t)row0 * E_DIM;

  int aoff[8];
#pragma unroll
  for (int rt = 0; rt < 8; ++rt) aoff[rt] = (rt * 16 + nl) * 64 + gs * 16;

  // A staging: thread -> rows (tid>>3, +64), float chunk c = tid&7 at k-offset 4c.
  // 8 lanes cover one full 128 B row-window (full-line coalescing).
  // bf16 dest: slot (c&3) swizzled, 8B half (c>>2).
  const int ar = tid >> 3, c = tid & 7;
  const int aw0 = ar * 64 + (((c & 3) ^ ((ar >> 1) & 3)) * 16) + (c >> 2) * 8;
  const int aw1 = aw0 + 64 * 64;  // row ar+64: same swizzle bits ((ar>>1)&3 invariant +32)
  const float* as0 = encA + (size_t)ar * E_DIM + c * 4;

  // B frags: wave w reads chunks (w*4 + ct)*1024 + lane*16 per step (contiguous 1 KB/wave)
  const char* bsrc = wsB + (w * 4) * 1024 + lane * 16;

  f32x4 acc[8][4];
#pragma unroll
  for (int rt = 0; rt < 8; ++rt)
#pragma unroll
    for (int ct = 0; ct < 4; ++ct) {
      f32x4 z = {0.f, 0.f, 0.f, 0.f};
      acc[rt][ct] = z;
    }
  f32x4 ra[4][2];     // A prefetch depth 4 (slot = kb & 3)
  bf16x8 bfr[2][4];   // B prefetch depth 1 (slot = kb & 1)

#define LOAD_A(kb_)                                                     \
  do {                                                                  \
    ra[(kb_) & 3][0] = *(const f32x4*)(as0 + (size_t)(kb_) * 32);       \
    ra[(kb_) & 3][1] = *(const f32x4*)(as0 + (size_t)(kb_) * 32 +       \
                                       (size_t)64 * E_DIM);             \
  } while (0)

#define LOAD_B(kb_)                                                     \
  do {                                                                  \
    _Pragma("unroll") for (int ct = 0; ct < 4; ++ct) bfr[(kb_) & 1][ct] = \
        *(const bf16x8*)(bsrc + (size_t)(kb_)*BCHUNK + ct * 1024);      \
  } while (0)

#define WRITE_A(kb_, dst_)                                              \
  do {                                                                  \
    *(u32x2*)(smem + (dst_) + aw0) = packbf(ra[(kb_) & 3][0]);          \
    *(u32x2*)(smem + (dst_) + aw1) = packbf(ra[(kb_) & 3][1]);          \
  } while (0)

#define COMPUTE(cur_, kb_)                                                   \
  do {                                                                       \
    bf16x8 afr[8];                                                           \
    _Pragma("unroll") for (int rt = 0; rt < 8; ++rt) afr[rt] =               \
        *(const bf16x8*)(smem + (cur_) + aoff[rt]);                          \
    __builtin_amdgcn_s_setprio(1);                                           \
    _Pragma("unroll") for (int rt = 0; rt < 8; ++rt)                         \
        _Pragma("unroll") for (int ct = 0; ct < 4; ++ct) acc[rt][ct] =       \
            __builtin_amdgcn_mfma_f32_16x16x32_bf16(afr[rt], bfr[(kb_)&1][ct], \
                                                    acc[rt][ct], 0, 0, 0);   \
    __builtin_amdgcn_s_setprio(0);                                           \
  } while (0)

  // ---- prologue: A0, B0, A1, A2, A3 (B-before-deep-A keeps later drains minimal)
  LOAD_A(0);
  LOAD_B(0);
  LOAD_A(1);
  LOAD_A(2);
  LOAD_A(3);
  asm volatile("s_waitcnt vmcnt(10)" ::: "memory");  // A0 done
  WRITE_A(0, 0);

  // ---- main loop: t = 0..27. Issue B(t+1) first, then A(t+4).
  // vmcnt(8) = prefix through B(t): completes A(t+1),A(t+2),B(t); leaves A(t+3),B(t+1),A(t+4).
#pragma unroll 4
  for (int t = 0; t < 28; ++t) {
    LOAD_B(t + 1);
    LOAD_A(t + 4);
    asm volatile("s_waitcnt vmcnt(8)" ::: "memory");
    WRITE_A(t + 1, ((t + 1) & 3) * BUFB);
    asm volatile("s_waitcnt lgkmcnt(0)" ::: "memory");
    asm volatile("s_barrier" ::: "memory");
    COMPUTE((t & 3) * BUFB, t);
  }
  // ---- t = 28: issue B(29); need A(29) (done), B(28) -> vmcnt(6)
  LOAD_B(29);
  asm volatile("s_waitcnt vmcnt(6)" ::: "memory");
  WRITE_A(29, 1 * BUFB);
  asm volatile("s_waitcnt lgkmcnt(0)" ::: "memory");
  asm volatile("s_barrier" ::: "memory");
  COMPUTE(0 * BUFB, 28);
  // ---- t = 29: issue B(30); need B(29) -> vmcnt(4)
  LOAD_B(30);
  asm volatile("s_waitcnt vmcnt(4)" ::: "memory");
  WRITE_A(30, 2 * BUFB);
  asm volatile("s_waitcnt lgkmcnt(0)" ::: "memory");
  asm volatile("s_barrier" ::: "memory");
  COMPUTE(1 * BUFB, 29);
  // ---- t = 30: issue B(31); need B(30) -> vmcnt(4)
  LOAD_B(31);
  asm volatile("s_waitcnt vmcnt(4)" ::: "memory");
  WRITE_A(31, 3 * BUFB);
  asm volatile("s_waitcnt lgkmcnt(0)" ::: "memory");
  asm volatile("s_barrier" ::: "memory");
  COMPUTE(2 * BUFB, 30);
  // ---- t = 31
  asm volatile("s_waitcnt vmcnt(0) lgkmcnt(0)" ::: "memory");
  asm volatile("s_barrier" ::: "memory");
  COMPUTE(3 * BUFB, 31);

#undef LOAD_A
#undef LOAD_B
#undef WRITE_A
#undef COMPUTE

  // epilogue: h = relu(acc + db), p = h·wf, reduce over 512 cols
  float db[4], wv[4];
#pragma unroll
  for (int ct = 0; ct < 4; ++ct) {
    int a = w * 64 + ct * 16 + nl;
    db[ct] = dcomb[bb * A_DIM + a];
    wv[ct] = wf[a];
  }
#pragma unroll
  for (int rt = 0; rt < 8; ++rt) {
#pragma unroll
    for (int r = 0; r < 4; ++r) {
      float p = 0.f;
#pragma unroll
      for (int ct = 0; ct < 4; ++ct) {
        float h = acc[rt][ct][r] + db[ct];
        h = h > 0.f ? h : 0.f;
        p += h * wv[ct];
      }
      p += __shfl_xor(p, 1);
      p += __shfl_xor(p, 2);
      p += __shfl_xor(p, 4);
      p += __shfl_xor(p, 8);
      if (nl == 0) atomicAdd(&s_score[rt * 16 + g * 4 + r], p);
    }
  }
  __syncthreads();
  if (tid < 128) scoreOut[row0 + tid] = s_score[tid];
}

// ---------------- K3: softmax over L per batch, in place -----------------------------------
__global__ void softmax_kernel(float* __restrict__ attn) {
  __shared__ float red[8];
  const int b = blockIdx.x, tid = threadIdx.x;
  float* p = attn + b * L_SEQ;
  float v[8];
  float m = -1e30f;
#pragma unroll
  for (int i = 0; i < 8; ++i) {
    v[i] = p[tid + i * 256];
    m = fmaxf(m, v[i]);
  }
#pragma unroll
  for (int off = 1; off < 64; off <<= 1) m = fmaxf(m, __shfl_xor(m, off));
  const int wid = tid >> 6;
  if ((tid & 63) == 0) red[wid] = m;
  __syncthreads();
  m = fmaxf(fmaxf(red[0], red[1]), fmaxf(red[2], red[3]));
  float s = 0.f;
#pragma unroll
  for (int i = 0; i < 8; ++i) {
    v[i] = __expf(v[i] - m);
    s += v[i];
  }
#pragma unroll
  for (int off = 1; off < 64; off <<= 1) s += __shfl_xor(s, off);
  __syncthreads();
  if ((tid & 63) == 0) red[4 + wid] = s;
  __syncthreads();
  const float inv = 1.0f / (red[4] + red[5] + red[6] + red[7]);
#pragma unroll
  for (int i = 0; i < 8; ++i) p[tid + i * 256] = v[i] * inv;
}

// ---------------- K4: weighted[b][e] = sum_l alpha[b][l] * enc[b][l][e] --------------------
__global__ void weighted_kernel(const float* __restrict__ enc, const float* __restrict__ alpha,
                                float* __restrict__ outW) {
  __shared__ float sa[64];
  const int bid = blockIdx.x;  // 2048 = 64 b * 32 l-segments of 64
  const int b = bid >> 5, ls = bid & 31;
  const int tid = threadIdx.x;
  if (tid < 64) sa[tid] = alpha[b * L_SEQ + ls * 64 + tid];
  __syncthreads();
  const f32x4* ep = (const f32x4*)(enc + ((size_t)(b * L_SEQ + ls * 64)) * E_DIM) + tid;
  f32x4 acc = {0.f, 0.f, 0.f, 0.f};
#pragma unroll 8
  for (int il = 0; il < 64; ++il) {
    f32x4 v = ep[(size_t)il * 256];
    float al = sa[il];
    acc.x += al * v.x;
    acc.y += al * v.y;
    acc.z += al * v.z;
    acc.w += al * v.w;
  }
  float* o = outW + b * E_DIM + tid * 4;
  atomicAdd(o + 0, acc.x);
  atomicAdd(o + 1, acc.y);
  atomicAdd(o + 2, acc.z);
  atomicAdd(o + 3, acc.w);
}

extern "C" void kernel_launch(void* const* d_in, const int* in_sizes, int n_in,
                              void* d_out, int out_size, void* d_ws, size_t ws_size,
                              hipStream_t stream) {
  const float* enc = (const float*)d_in[0];
  const float* dh = (const float*)d_in[1];
  const float* WeW = (const float*)d_in[2];
  const float* WeB = (const float*)d_in[3];
  const float* WdW = (const float*)d_in[4];
  const float* WdB = (const float*)d_in[5];
  const float* WfW = (const float*)d_in[6];
  // Wf_b (d_in[7]) irrelevant: softmax is shift-invariant and attn isn't an output.

  float* out = (float*)d_out;
  float* outW = out;                      // weighted: 64*1024
  float* attn = out + B_BATCH * E_DIM;    // scores -> alpha: 64*2048

  char* wsB = (char*)d_ws;                                     // 32 * 32768 = 1 MB
  float* dcomb = (float*)((char*)d_ws + 32 * (size_t)BCHUNK);  // 64*512 fp32

  if (ws_size < 32 * (size_t)BCHUNK + (size_t)B_BATCH * A_DIM * sizeof(float)) return;

  hipMemsetAsync(outW, 0, (size_t)(B_BATCH * E_DIM) * sizeof(float), stream);
  prep_we_kernel<<<256, 256, 0, stream>>>(WeW, wsB);
  dec_comb_kernel<<<dim3(B_BATCH, 2), 256, 0, stream>>>(dh, WdW, WdB, WeB, dcomb);
  score_gemm_kernel<<<(B_BATCH * L_SEQ) / 128, 512, 0, stream>>>(enc, wsB, dcomb, WfW, attn);
  softmax_kernel<<<B_BATCH, 256, 0, stream>>>(attn);
  weighted_kernel<<<B_BATCH * 32, 256, 0, stream>>>(enc, attn, outW);
}